// Round 14
// baseline (158.420 us; speedup 1.0000x reference)
//
#include <hip/hip_runtime.h>
#include <math.h>

// Problem constants (fixed by the reference)
#define BATCH 2
#define NQ    300
#define NC    80
#define NFLAT (NQ * NC)     // 24000 per batch
#define TOPK  300
#define HM    128           // mask H=W
#define OUTS  480           // output H=W
#define NBKT  4096          // histogram buckets (top 12 bits of mapped float)
#define CAP   4096          // candidate capacity

#define INVSCALEF 0.26666668f  // 128/480 in f32; resize coords are never within
                               // 1/30 of an integer, so f32 floor/frac are exact

typedef float v4f __attribute__((ext_vector_type(4)));
typedef unsigned long long ull;

// order-preserving map: float bits -> uint32 (monotone in float value)
__device__ __forceinline__ unsigned mapf(float x) {
    unsigned u = __float_as_uint(x);
    return (u & 0x80000000u) ? ~u : (u | 0x80000000u);
}

// ---------------------------------------------------------------------------
// Kernel 1: FUSED top-k. One block per batch sample. (byte-identical to R12)
// ---------------------------------------------------------------------------
__global__ __launch_bounds__(1024) void topk_kernel(
    const float* __restrict__ logits,   // [B,Q,C]
    const float* __restrict__ boxes,    // [B,Q,4] cxcywh
    const float* __restrict__ osize,    // [B,2]
    float* __restrict__ out,            // header region of d_out
    int* __restrict__ qidx)             // [B*K] scratch (ws)
{
    __shared__ unsigned hist[NBKT];              // 16 KB
    __shared__ unsigned long long cand[CAP];     // 32 KB
    __shared__ unsigned wtot[16];
    __shared__ unsigned ysuf[17];
    __shared__ unsigned sh_T;
    __shared__ unsigned sh_cnt;

    const int b = blockIdx.x;
    const int tid = threadIdx.x;
    const int lane = tid & 63;
    const int w = tid >> 6;
    const float* lg = logits + (size_t)b * NFLAT;
    const v4f* lg4 = (const v4f*)lg;

    // zero the histogram (each thread owns 4 consecutive buckets)
    *(uint4*)&hist[4 * tid] = make_uint4(0u, 0u, 0u, 0u);
    if (tid == 0) sh_cnt = 0;
    __syncthreads();

    // histogram of top 12 bits of the mapped float (float4 loads, LDS atomics)
    for (int i4 = tid; i4 < NFLAT / 4; i4 += 1024) {
        const v4f v = lg4[i4];
        atomicAdd(&hist[mapf(v.x) >> 20], 1u);
        atomicAdd(&hist[mapf(v.y) >> 20], 1u);
        atomicAdd(&hist[mapf(v.z) >> 20], 1u);
        atomicAdd(&hist[mapf(v.w) >> 20], 1u);
    }
    __syncthreads();

    // this thread's 4 buckets
    const uint4 h4 = *(const uint4*)&hist[4 * tid];
    const unsigned gsum = h4.x + h4.y + h4.z + h4.w;

    // wave-level inclusive suffix scan of gsum
    unsigned s = gsum;
    #pragma unroll
    for (int off = 1; off < 64; off <<= 1) {
        unsigned v = __shfl_down(s, off, 64);
        if (lane + off < 64) s += v;
    }
    if (lane == 0) wtot[w] = s;    // wave total
    __syncthreads();
    if (tid == 0) {                // suffix over 16 wave totals
        unsigned acc = 0;
        ysuf[16] = 0;
        for (int i = 15; i >= 0; --i) { acc += wtot[i]; ysuf[i] = acc; }
    }
    __syncthreads();
    const unsigned S   = s + ysuf[w + 1];  // #{elements in buckets >= 4*tid}
    const unsigned nxt = S - gsum;         // #{elements in buckets >  4*tid+3}
    if (S >= (unsigned)TOPK && nxt < (unsigned)TOPK) {
        unsigned acc = nxt, T;
        if (acc + h4.w >= (unsigned)TOPK) T = 4u * tid + 3u;
        else { acc += h4.w;
            if (acc + h4.z >= (unsigned)TOPK) T = 4u * tid + 2u;
            else { acc += h4.z;
                if (acc + h4.y >= (unsigned)TOPK) T = 4u * tid + 1u;
                else T = 4u * tid;
            }
        }
        sh_T = T;
    }
    __syncthreads();
    const unsigned T = sh_T;

    // collect candidates (bucket >= T): float4 loads (L2-warm);
    // keys = score desc, idx asc
    for (int i4 = tid; i4 < NFLAT / 4; i4 += 1024) {
        const v4f v = lg4[i4];
        #pragma unroll
        for (int j = 0; j < 4; ++j) {
            const unsigned m = mapf(v[j]);
            if ((m >> 20) >= T) {
                unsigned pos = atomicAdd(&sh_cnt, 1u);
                if (pos < CAP) {
                    const unsigned idx = 4u * i4 + j;
                    cand[pos] = ((ull)m << 32) | (ull)(0xFFFFFFFFu - idx);
                }
            }
        }
    }
    __syncthreads();
    const unsigned cnt = (sh_cnt > CAP) ? CAP : sh_cnt;

    // rank-select: rank = #{keys greater than mine}; ranks are unique.
    for (unsigned t = tid; t < cnt; t += 1024) {
        const unsigned long long my = cand[t];
        unsigned rank = 0;
        for (unsigned j = 0; j < cnt; ++j) rank += (cand[j] > my) ? 1u : 0u;
        if (rank < (unsigned)TOPK) {
            const unsigned idx = 0xFFFFFFFFu - (unsigned)(my & 0xFFFFFFFFull);
            const int q = (int)(idx / NC);
            const int c = (int)(idx % NC);
            const double x = (double)lg[idx];
            const double score = 1.0 / (1.0 + exp(-x));

            out[b * TOPK + rank] = (float)score;                   // top_scores
            out[BATCH * TOPK + b * TOPK + rank] = (float)c;        // top_labels

            const float* bx = boxes + ((size_t)(b * NQ + q)) * 4;
            const double cx = (double)bx[0], cy = (double)bx[1];
            const double bw = (double)bx[2], bh = (double)bx[3];
            const double s0 = (double)osize[b * 2 + 0];
            const double s1 = (double)osize[b * 2 + 1];
            float* ob = out + 2 * BATCH * TOPK + ((size_t)(b * TOPK + rank)) * 4;
            ob[0] = (float)((cx - 0.5 * bw) * s0);
            ob[1] = (float)((cy - 0.5 * bh) * s1);
            ob[2] = (float)((cx + 0.5 * bw) * s0);
            ob[3] = (float)((cy + 0.5 * bh) * s1);

            qidx[b * TOPK + rank] = q;
        }
    }
}

// ---------------------------------------------------------------------------
// Kernel 2: gather masks, sigmoid, bilinear 128->480, threshold. All f32.
// One small block per (mask, 16-row slice): 600*30 = 18000 blocks x 256 thr.
// (exact R7/R8/R10/R12 proven version — byte-identical)
// ---------------------------------------------------------------------------
#define VROWS   16
#define NVS     (OUTS / VROWS)       // 30 slices per mask
#define MAXR    6                    // max source rows per slice

__global__ __launch_bounds__(256) void mask_kernel(
    const float* __restrict__ masks,   // [B,Q,128,128]
    const int* __restrict__ qidx,      // [B*K]
    float* __restrict__ outm)          // d_out + 3600, [B*K,480,480]
{
    __shared__ float sig[MAXR * HM];   // 3 KB

    const int tid = threadIdx.x;
    const int unit = blockIdx.x;
    const int mask_id = unit / NVS;
    const int vs = unit % NVS;
    const int ys = vs * VROWS;
    const int b = mask_id / TOPK;
    const int q = qidx[mask_id];

    // source row range for this slice (f32 floor is exact here)
    float s_first = ((float)ys + 0.5f) * INVSCALEF - 0.5f;
    float s_last  = ((float)(ys + VROWS - 1) + 0.5f) * INVSCALEF - 0.5f;
    int r_lo = (int)floorf(s_first);
    if (r_lo < 0) r_lo = 0; if (r_lo > HM - 2) r_lo = HM - 2;
    int r_hi = (int)floorf(s_last);
    if (r_hi < 0) r_hi = 0; if (r_hi > HM - 2) r_hi = HM - 2;
    r_hi += 1;
    const int cnt = r_hi - r_lo + 1;   // <= 6

    // stage source rows [r_lo, r_hi] as f32 sigmoid (one 16B load/thread)
    const v4f* s4 = (const v4f*)(masks
                      + ((size_t)(b * NQ + q)) * (HM * HM)
                      + (size_t)r_lo * HM);
    const int n4 = cnt * (HM / 4);     // <= 192
    if (tid < n4) {
        v4f v = s4[tid];
        float* dst = sig + tid * 4;
        dst[0] = 1.0f / (1.0f + __expf(-v.x));
        dst[1] = 1.0f / (1.0f + __expf(-v.y));
        dst[2] = 1.0f / (1.0f + __expf(-v.z));
        dst[3] = 1.0f / (1.0f + __expf(-v.w));
    }

    // per-thread column geometry (threads 0..239 active: 2 rows x 120 quads)
    const int qd = tid % 120;
    const int yy = tid / 120;          // 0 or 1
    const int x0 = qd * 4;
    int c0 = 0, ar[4];
    float fxr[4];
    #pragma unroll
    for (int j = 0; j < 4; ++j) {
        float sx = ((float)(x0 + j) + 0.5f) * INVSCALEF - 0.5f;
        int jx = (int)floorf(sx);
        if (jx < 0) jx = 0; if (jx > HM - 2) jx = HM - 2;
        float f = sx - (float)jx;
        f = fminf(fmaxf(f, 0.0f), 1.0f);
        if (j == 0) c0 = jx;
        ar[j]  = jx - c0;              // 0 or 1
        fxr[j] = f;
    }
    const int c1 = c0 + 1;
    const int c2 = (c0 + 2 > HM - 1) ? (HM - 1) : (c0 + 2);

    __syncthreads();

    if (tid < 240) {
        float* outp = outm + (size_t)mask_id * (OUTS * OUTS)
                           + (size_t)(ys + yy) * OUTS + x0;
        #pragma unroll
        for (int it = 0; it < VROWS / 2; ++it) {
            const int y = ys + yy + it * 2;
            float sy = ((float)y + 0.5f) * INVSCALEF - 0.5f;
            int jy = (int)floorf(sy);
            if (jy < 0) jy = 0; if (jy > HM - 2) jy = HM - 2;
            float fy = sy - (float)jy;
            fy = fminf(fmaxf(fy, 0.0f), 1.0f);

            const float* r0 = sig + (size_t)(jy - r_lo) * HM;
            const float* r1 = r0 + HM;
            const float wy1 = fy, wy0 = 1.0f - fy;

            const float t0 = wy0 * r0[c0] + wy1 * r1[c0];
            const float t1 = wy0 * r0[c1] + wy1 * r1[c1];
            const float t2 = wy0 * r0[c2] + wy1 * r1[c2];

            v4f res;
            #pragma unroll
            for (int j = 0; j < 4; ++j) {
                const float ta = ar[j] ? t1 : t0;
                const float tb = ar[j] ? t2 : t1;
                const float val = ta + fxr[j] * (tb - ta);
                res[j] = (val > 0.5f) ? 1.0f : 0.0f;
            }
            *((v4f*)(outp + (size_t)(it * 2) * OUTS)) = res;
        }
    }
}

// ---------------------------------------------------------------------------
// R14 = R12 with topk_kernel launched TWICE (idempotent; second launch is a
// direct on-device measurement of the fused topk's steady-state duration:
// dur_us(R14) - dur_us(R12) = topk + launch gap).
// ---------------------------------------------------------------------------
extern "C" void kernel_launch(void* const* d_in, const int* in_sizes, int n_in,
                              void* d_out, int out_size, void* d_ws, size_t ws_size,
                              hipStream_t stream) {
    const float* logits = (const float*)d_in[0];   // [2,300,80]
    const float* boxes  = (const float*)d_in[1];   // [2,300,4]
    const float* masks  = (const float*)d_in[2];   // [2,300,128,128]
    const float* osize  = (const float*)d_in[3];   // [2,2]
    float* out = (float*)d_out;
    int* qidx = (int*)d_ws;                        // 600 ints

    topk_kernel<<<BATCH, 1024, 0, stream>>>(logits, boxes, osize, out, qidx);
    topk_kernel<<<BATCH, 1024, 0, stream>>>(logits, boxes, osize, out, qidx);

    // masks start after scores(600) + labels(600) + boxes(2400) = 3600 floats
    mask_kernel<<<BATCH * TOPK * NVS, 256, 0, stream>>>(masks, qidx, out + 3600);
}

// Round 15
// 142.620 us; speedup vs baseline: 1.1108x; 1.1108x over previous
//
#include <hip/hip_runtime.h>
#include <math.h>

// Problem constants (fixed by the reference)
#define BATCH 2
#define NQ    300
#define NC    80
#define NFLAT (NQ * NC)     // 24000 per batch
#define TOPK  300
#define HM    128           // mask H=W
#define OUTS  480           // output H=W
#define NBKT  256           // coarse histogram buckets (top 8 bits of mapped float)
#define CAP   4096          // candidate capacity (cnt ~<1k for coarse threshold)

#define INVSCALEF 0.26666668f  // 128/480 in f32; resize coords are never within
                               // 1/30 of an integer, so f32 floor/frac are exact

typedef float v4f __attribute__((ext_vector_type(4)));
typedef unsigned long long ull;

// order-preserving map: float bits -> uint32 (monotone in float value)
__device__ __forceinline__ unsigned mapf(float x) {
    unsigned u = __float_as_uint(x);
    return (u & 0x80000000u) ? ~u : (u | 0x80000000u);
}

// ---------------------------------------------------------------------------
// Kernel 1: FUSED top-k, minimum-phase design. One block per batch sample.
// 3 barriers total: {zero | hist | collect} ; threshold found wave-locally
// in registers (no block scan, no serial thread-0 code).
// ---------------------------------------------------------------------------
__global__ __launch_bounds__(1024) void topk_kernel(
    const float* __restrict__ logits,   // [B,Q,C]
    const float* __restrict__ boxes,    // [B,Q,4] cxcywh
    const float* __restrict__ osize,    // [B,2]
    float* __restrict__ out,            // header region of d_out
    int* __restrict__ qidx)             // [B*K] scratch (ws)
{
    __shared__ unsigned hist[NBKT];              // 1 KB
    __shared__ unsigned long long cand[CAP];     // 32 KB
    __shared__ unsigned sh_cnt;

    const int b = blockIdx.x;
    const int tid = threadIdx.x;
    const int lane = tid & 63;
    const float* lg = logits + (size_t)b * NFLAT;
    const v4f* lg4 = (const v4f*)lg;

    // phase 0: zero
    if (tid < NBKT / 4) *(uint4*)&hist[4 * tid] = make_uint4(0u, 0u, 0u, 0u);
    if (tid == 1023) sh_cnt = 0;
    __syncthreads();                                           // barrier 1

    // phase 1: coarse histogram (top 8 bits of mapped float)
    for (int i4 = tid; i4 < NFLAT / 4; i4 += 1024) {
        const v4f v = lg4[i4];
        atomicAdd(&hist[mapf(v.x) >> 24], 1u);
        atomicAdd(&hist[mapf(v.y) >> 24], 1u);
        atomicAdd(&hist[mapf(v.z) >> 24], 1u);
        atomicAdd(&hist[mapf(v.w) >> 24], 1u);
    }
    __syncthreads();                                           // barrier 2

    // phase 2 (no barrier): every wave redundantly finds threshold bucket T.
    // lane l owns buckets [4l, 4l+3]; inclusive suffix scan of group sums.
    const uint4 h4 = *(const uint4*)&hist[4 * lane];
    const unsigned c4 = h4.x + h4.y + h4.z + h4.w;
    unsigned sfx = c4;
    #pragma unroll
    for (int off = 1; off < 64; off <<= 1) {
        unsigned v = __shfl_down(sfx, off, 64);
        if (lane + off < 64) sfx += v;
    }
    const unsigned nxt = sfx - c4;       // count in buckets > 4*lane+3
    const bool found = (sfx >= (unsigned)TOPK) && (nxt < (unsigned)TOPK);
    unsigned Tloc = 0;
    if (found) {
        unsigned acc = nxt;
        if (acc + h4.w >= (unsigned)TOPK) Tloc = 4u * lane + 3u;
        else { acc += h4.w;
            if (acc + h4.z >= (unsigned)TOPK) Tloc = 4u * lane + 2u;
            else { acc += h4.z;
                if (acc + h4.y >= (unsigned)TOPK) Tloc = 4u * lane + 1u;
                else Tloc = 4u * lane;
            }
        }
    }
    const ull fmask = __ballot(found);
    const int src = __ffsll(fmask) - 1;          // exactly one lane per wave
    const unsigned T = __shfl(Tloc, src, 64);

    // phase 3: collect candidates (coarse bucket >= T); superset of top-K,
    // rank-select below restores exactness. keys = score desc, idx asc.
    for (int i4 = tid; i4 < NFLAT / 4; i4 += 1024) {
        const v4f v = lg4[i4];
        #pragma unroll
        for (int j = 0; j < 4; ++j) {
            const unsigned m = mapf(v[j]);
            if ((m >> 24) >= T) {
                unsigned pos = atomicAdd(&sh_cnt, 1u);
                if (pos < CAP) {
                    const unsigned idx = 4u * i4 + j;
                    cand[pos] = ((ull)m << 32) | (ull)(0xFFFFFFFFu - idx);
                }
            }
        }
    }
    __syncthreads();                                           // barrier 3
    const unsigned cnt = (sh_cnt > CAP) ? CAP : sh_cnt;

    // phase 4: rank-select (rank = #{keys greater than mine}; unique) + emit
    for (unsigned t = tid; t < cnt; t += 1024) {
        const unsigned long long my = cand[t];
        unsigned rank = 0;
        for (unsigned j = 0; j < cnt; ++j) rank += (cand[j] > my) ? 1u : 0u;
        if (rank < (unsigned)TOPK) {
            const unsigned idx = 0xFFFFFFFFu - (unsigned)(my & 0xFFFFFFFFull);
            const int q = (int)(idx / NC);
            const int c = (int)(idx % NC);
            const double x = (double)lg[idx];
            const double score = 1.0 / (1.0 + exp(-x));

            out[b * TOPK + rank] = (float)score;                   // top_scores
            out[BATCH * TOPK + b * TOPK + rank] = (float)c;        // top_labels

            const float* bx = boxes + ((size_t)(b * NQ + q)) * 4;
            const double cx = (double)bx[0], cy = (double)bx[1];
            const double bw = (double)bx[2], bh = (double)bx[3];
            const double s0 = (double)osize[b * 2 + 0];
            const double s1 = (double)osize[b * 2 + 1];
            float* ob = out + 2 * BATCH * TOPK + ((size_t)(b * TOPK + rank)) * 4;
            ob[0] = (float)((cx - 0.5 * bw) * s0);
            ob[1] = (float)((cy - 0.5 * bh) * s1);
            ob[2] = (float)((cx + 0.5 * bw) * s0);
            ob[3] = (float)((cy + 0.5 * bh) * s1);

            qidx[b * TOPK + rank] = q;
        }
    }
}

// ---------------------------------------------------------------------------
// Kernel 2: gather masks, sigmoid, bilinear 128->480, threshold. All f32.
// One small block per (mask, 16-row slice): 600*30 = 18000 blocks x 256 thr.
// (exact R7/R8/R10/R12 proven version — byte-identical)
// ---------------------------------------------------------------------------
#define VROWS   16
#define NVS     (OUTS / VROWS)       // 30 slices per mask
#define MAXR    6                    // max source rows per slice

__global__ __launch_bounds__(256) void mask_kernel(
    const float* __restrict__ masks,   // [B,Q,128,128]
    const int* __restrict__ qidx,      // [B*K]
    float* __restrict__ outm)          // d_out + 3600, [B*K,480,480]
{
    __shared__ float sig[MAXR * HM];   // 3 KB

    const int tid = threadIdx.x;
    const int unit = blockIdx.x;
    const int mask_id = unit / NVS;
    const int vs = unit % NVS;
    const int ys = vs * VROWS;
    const int b = mask_id / TOPK;
    const int q = qidx[mask_id];

    // source row range for this slice (f32 floor is exact here)
    float s_first = ((float)ys + 0.5f) * INVSCALEF - 0.5f;
    float s_last  = ((float)(ys + VROWS - 1) + 0.5f) * INVSCALEF - 0.5f;
    int r_lo = (int)floorf(s_first);
    if (r_lo < 0) r_lo = 0; if (r_lo > HM - 2) r_lo = HM - 2;
    int r_hi = (int)floorf(s_last);
    if (r_hi < 0) r_hi = 0; if (r_hi > HM - 2) r_hi = HM - 2;
    r_hi += 1;
    const int cnt = r_hi - r_lo + 1;   // <= 6

    // stage source rows [r_lo, r_hi] as f32 sigmoid (one 16B load/thread)
    const v4f* s4 = (const v4f*)(masks
                      + ((size_t)(b * NQ + q)) * (HM * HM)
                      + (size_t)r_lo * HM);
    const int n4 = cnt * (HM / 4);     // <= 192
    if (tid < n4) {
        v4f v = s4[tid];
        float* dst = sig + tid * 4;
        dst[0] = 1.0f / (1.0f + __expf(-v.x));
        dst[1] = 1.0f / (1.0f + __expf(-v.y));
        dst[2] = 1.0f / (1.0f + __expf(-v.z));
        dst[3] = 1.0f / (1.0f + __expf(-v.w));
    }

    // per-thread column geometry (threads 0..239 active: 2 rows x 120 quads)
    const int qd = tid % 120;
    const int yy = tid / 120;          // 0 or 1
    const int x0 = qd * 4;
    int c0 = 0, ar[4];
    float fxr[4];
    #pragma unroll
    for (int j = 0; j < 4; ++j) {
        float sx = ((float)(x0 + j) + 0.5f) * INVSCALEF - 0.5f;
        int jx = (int)floorf(sx);
        if (jx < 0) jx = 0; if (jx > HM - 2) jx = HM - 2;
        float f = sx - (float)jx;
        f = fminf(fmaxf(f, 0.0f), 1.0f);
        if (j == 0) c0 = jx;
        ar[j]  = jx - c0;              // 0 or 1
        fxr[j] = f;
    }
    const int c1 = c0 + 1;
    const int c2 = (c0 + 2 > HM - 1) ? (HM - 1) : (c0 + 2);

    __syncthreads();

    if (tid < 240) {
        float* outp = outm + (size_t)mask_id * (OUTS * OUTS)
                           + (size_t)(ys + yy) * OUTS + x0;
        #pragma unroll
        for (int it = 0; it < VROWS / 2; ++it) {
            const int y = ys + yy + it * 2;
            float sy = ((float)y + 0.5f) * INVSCALEF - 0.5f;
            int jy = (int)floorf(sy);
            if (jy < 0) jy = 0; if (jy > HM - 2) jy = HM - 2;
            float fy = sy - (float)jy;
            fy = fminf(fmaxf(fy, 0.0f), 1.0f);

            const float* r0 = sig + (size_t)(jy - r_lo) * HM;
            const float* r1 = r0 + HM;
            const float wy1 = fy, wy0 = 1.0f - fy;

            const float t0 = wy0 * r0[c0] + wy1 * r1[c0];
            const float t1 = wy0 * r0[c1] + wy1 * r1[c1];
            const float t2 = wy0 * r0[c2] + wy1 * r1[c2];

            v4f res;
            #pragma unroll
            for (int j = 0; j < 4; ++j) {
                const float ta = ar[j] ? t1 : t0;
                const float tb = ar[j] ? t2 : t1;
                const float val = ta + fxr[j] * (tb - ta);
                res[j] = (val > 0.5f) ? 1.0f : 0.0f;
            }
            *((v4f*)(outp + (size_t)(it * 2) * OUTS)) = res;
        }
    }
}

// ---------------------------------------------------------------------------
extern "C" void kernel_launch(void* const* d_in, const int* in_sizes, int n_in,
                              void* d_out, int out_size, void* d_ws, size_t ws_size,
                              hipStream_t stream) {
    const float* logits = (const float*)d_in[0];   // [2,300,80]
    const float* boxes  = (const float*)d_in[1];   // [2,300,4]
    const float* masks  = (const float*)d_in[2];   // [2,300,128,128]
    const float* osize  = (const float*)d_in[3];   // [2,2]
    float* out = (float*)d_out;
    int* qidx = (int*)d_ws;                        // 600 ints

    topk_kernel<<<BATCH, 1024, 0, stream>>>(logits, boxes, osize, out, qidx);

    // masks start after scores(600) + labels(600) + boxes(2400) = 3600 floats
    mask_kernel<<<BATCH * TOPK * NVS, 256, 0, stream>>>(masks, qidx, out + 3600);
}

// Round 16
// 141.860 us; speedup vs baseline: 1.1167x; 1.0054x over previous
//
#include <hip/hip_runtime.h>
#include <math.h>

// Problem constants (fixed by the reference)
#define BATCH 2
#define NQ    300
#define NC    80
#define NFLAT (NQ * NC)     // 24000 per batch
#define TOPK  300
#define HM    128           // mask H=W
#define OUTS  480           // output H=W
#define NBKT  4096          // histogram buckets (top 12 bits of mapped float)
#define CAP   4096          // candidate capacity

#define INVSCALEF 0.26666668f  // 128/480 in f32; resize coords are never within
                               // 1/30 of an integer, so f32 floor/frac are exact

typedef float v4f __attribute__((ext_vector_type(4)));
typedef unsigned long long ull;

// order-preserving map: float bits -> uint32 (monotone in float value)
__device__ __forceinline__ unsigned mapf(float x) {
    unsigned u = __float_as_uint(x);
    return (u & 0x80000000u) ? ~u : (u | 0x80000000u);
}

// ---------------------------------------------------------------------------
// Kernel 1: FUSED top-k. One block per batch sample.
// (byte-identical to R12 — measured 17 us; R15's variant regressed)
// ---------------------------------------------------------------------------
__global__ __launch_bounds__(1024) void topk_kernel(
    const float* __restrict__ logits,   // [B,Q,C]
    const float* __restrict__ boxes,    // [B,Q,4] cxcywh
    const float* __restrict__ osize,    // [B,2]
    float* __restrict__ out,            // header region of d_out
    int* __restrict__ qidx)             // [B*K] scratch (ws)
{
    __shared__ unsigned hist[NBKT];              // 16 KB
    __shared__ unsigned long long cand[CAP];     // 32 KB
    __shared__ unsigned wtot[16];
    __shared__ unsigned ysuf[17];
    __shared__ unsigned sh_T;
    __shared__ unsigned sh_cnt;

    const int b = blockIdx.x;
    const int tid = threadIdx.x;
    const int lane = tid & 63;
    const int w = tid >> 6;
    const float* lg = logits + (size_t)b * NFLAT;
    const v4f* lg4 = (const v4f*)lg;

    // zero the histogram (each thread owns 4 consecutive buckets)
    *(uint4*)&hist[4 * tid] = make_uint4(0u, 0u, 0u, 0u);
    if (tid == 0) sh_cnt = 0;
    __syncthreads();

    // histogram of top 12 bits of the mapped float (float4 loads, LDS atomics)
    for (int i4 = tid; i4 < NFLAT / 4; i4 += 1024) {
        const v4f v = lg4[i4];
        atomicAdd(&hist[mapf(v.x) >> 20], 1u);
        atomicAdd(&hist[mapf(v.y) >> 20], 1u);
        atomicAdd(&hist[mapf(v.z) >> 20], 1u);
        atomicAdd(&hist[mapf(v.w) >> 20], 1u);
    }
    __syncthreads();

    // this thread's 4 buckets
    const uint4 h4 = *(const uint4*)&hist[4 * tid];
    const unsigned gsum = h4.x + h4.y + h4.z + h4.w;

    // wave-level inclusive suffix scan of gsum
    unsigned s = gsum;
    #pragma unroll
    for (int off = 1; off < 64; off <<= 1) {
        unsigned v = __shfl_down(s, off, 64);
        if (lane + off < 64) s += v;
    }
    if (lane == 0) wtot[w] = s;    // wave total
    __syncthreads();
    if (tid == 0) {                // suffix over 16 wave totals
        unsigned acc = 0;
        ysuf[16] = 0;
        for (int i = 15; i >= 0; --i) { acc += wtot[i]; ysuf[i] = acc; }
    }
    __syncthreads();
    const unsigned S   = s + ysuf[w + 1];  // #{elements in buckets >= 4*tid}
    const unsigned nxt = S - gsum;         // #{elements in buckets >  4*tid+3}
    if (S >= (unsigned)TOPK && nxt < (unsigned)TOPK) {
        unsigned acc = nxt, T;
        if (acc + h4.w >= (unsigned)TOPK) T = 4u * tid + 3u;
        else { acc += h4.w;
            if (acc + h4.z >= (unsigned)TOPK) T = 4u * tid + 2u;
            else { acc += h4.z;
                if (acc + h4.y >= (unsigned)TOPK) T = 4u * tid + 1u;
                else T = 4u * tid;
            }
        }
        sh_T = T;
    }
    __syncthreads();
    const unsigned T = sh_T;

    // collect candidates (bucket >= T): float4 loads (L2-warm);
    // keys = score desc, idx asc
    for (int i4 = tid; i4 < NFLAT / 4; i4 += 1024) {
        const v4f v = lg4[i4];
        #pragma unroll
        for (int j = 0; j < 4; ++j) {
            const unsigned m = mapf(v[j]);
            if ((m >> 20) >= T) {
                unsigned pos = atomicAdd(&sh_cnt, 1u);
                if (pos < CAP) {
                    const unsigned idx = 4u * i4 + j;
                    cand[pos] = ((ull)m << 32) | (ull)(0xFFFFFFFFu - idx);
                }
            }
        }
    }
    __syncthreads();
    const unsigned cnt = (sh_cnt > CAP) ? CAP : sh_cnt;

    // rank-select: rank = #{keys greater than mine}; ranks are unique.
    for (unsigned t = tid; t < cnt; t += 1024) {
        const unsigned long long my = cand[t];
        unsigned rank = 0;
        for (unsigned j = 0; j < cnt; ++j) rank += (cand[j] > my) ? 1u : 0u;
        if (rank < (unsigned)TOPK) {
            const unsigned idx = 0xFFFFFFFFu - (unsigned)(my & 0xFFFFFFFFull);
            const int q = (int)(idx / NC);
            const int c = (int)(idx % NC);
            const double x = (double)lg[idx];
            const double score = 1.0 / (1.0 + exp(-x));

            out[b * TOPK + rank] = (float)score;                   // top_scores
            out[BATCH * TOPK + b * TOPK + rank] = (float)c;        // top_labels

            const float* bx = boxes + ((size_t)(b * NQ + q)) * 4;
            const double cx = (double)bx[0], cy = (double)bx[1];
            const double bw = (double)bx[2], bh = (double)bx[3];
            const double s0 = (double)osize[b * 2 + 0];
            const double s1 = (double)osize[b * 2 + 1];
            float* ob = out + 2 * BATCH * TOPK + ((size_t)(b * TOPK + rank)) * 4;
            ob[0] = (float)((cx - 0.5 * bw) * s0);
            ob[1] = (float)((cy - 0.5 * bh) * s1);
            ob[2] = (float)((cx + 0.5 * bw) * s0);
            ob[3] = (float)((cy + 0.5 * bh) * s1);

            qidx[b * TOPK + rank] = q;
        }
    }
}

// ---------------------------------------------------------------------------
// Kernel 2: mask upsample, TWO-STAGE interpolation.
// Same grid/staging as the proven R12 version (18000 blocks x 256 thr,
// one block per (mask, 16-row slice)), but the vertical lerp is computed
// ONCE per (row,col) into tmp[16][128] with vectorized b128 LDS ops
// (phase B), so the per-quad inner loop (phase C) drops from
// 6 LDS reads + ~39 VALU to 3 LDS reads + ~24 VALU.
// ---------------------------------------------------------------------------
#define VROWS   16
#define NVS     (OUTS / VROWS)       // 30 slices per mask
#define MAXR    6                    // max source rows per slice

__global__ __launch_bounds__(256) void mask_kernel(
    const float* __restrict__ masks,   // [B,Q,128,128]
    const int* __restrict__ qidx,      // [B*K]
    float* __restrict__ outm)          // d_out + 3600, [B*K,480,480]
{
    __shared__ __align__(16) float sig[MAXR * HM];    // 3 KB: sigmoid rows
    __shared__ __align__(16) float tmp[VROWS * HM];   // 8 KB: vertically-lerped rows

    const int tid = threadIdx.x;
    const int unit = blockIdx.x;
    const int mask_id = unit / NVS;
    const int vs = unit % NVS;
    const int ys = vs * VROWS;
    const int b = mask_id / TOPK;
    const int q = qidx[mask_id];

    // source row range for this slice (f32 floor is exact here)
    float s_first = ((float)ys + 0.5f) * INVSCALEF - 0.5f;
    float s_last  = ((float)(ys + VROWS - 1) + 0.5f) * INVSCALEF - 0.5f;
    int r_lo = (int)floorf(s_first);
    if (r_lo < 0) r_lo = 0; if (r_lo > HM - 2) r_lo = HM - 2;
    int r_hi = (int)floorf(s_last);
    if (r_hi < 0) r_hi = 0; if (r_hi > HM - 2) r_hi = HM - 2;
    r_hi += 1;
    const int cnt = r_hi - r_lo + 1;   // <= 6

    // phase A: stage source rows [r_lo, r_hi] as f32 sigmoid (16B load+store)
    const v4f* s4 = (const v4f*)(masks
                      + ((size_t)(b * NQ + q)) * (HM * HM)
                      + (size_t)r_lo * HM);
    const int n4 = cnt * (HM / 4);     // <= 192
    if (tid < n4) {
        v4f v = s4[tid];
        v4f r;
        r.x = 1.0f / (1.0f + __expf(-v.x));
        r.y = 1.0f / (1.0f + __expf(-v.y));
        r.z = 1.0f / (1.0f + __expf(-v.z));
        r.w = 1.0f / (1.0f + __expf(-v.w));
        *((v4f*)(sig + tid * 4)) = r;
    }

    // per-thread column geometry (fixed per tid; used in phase C)
    const int qd = tid % 120;
    const int yy0 = tid / 120;         // 0 or 1 (threads 0..239 active in C)
    const int x0 = qd * 4;
    int c0 = 0, ar[4];
    float fxr[4];
    #pragma unroll
    for (int j = 0; j < 4; ++j) {
        float sx = ((float)(x0 + j) + 0.5f) * INVSCALEF - 0.5f;
        int jx = (int)floorf(sx);
        if (jx < 0) jx = 0; if (jx > HM - 2) jx = HM - 2;
        float f = sx - (float)jx;
        f = fminf(fmaxf(f, 0.0f), 1.0f);
        if (j == 0) c0 = jx;
        ar[j]  = jx - c0;              // 0 or 1
        fxr[j] = f;
    }
    const int c1 = c0 + 1;
    const int c2 = (c0 + 2 > HM - 1) ? (HM - 1) : (c0 + 2);

    __syncthreads();

    // phase B: vertical lerp once per (row,col4): 512 v4f units, 2 per thread
    #pragma unroll
    for (int k = 0; k < 2; ++k) {
        const int u = tid + 256 * k;          // 0..511
        const int yy = u >> 5;                // output row 0..15
        const int col4 = (u & 31);            // v4f column 0..31
        const int y = ys + yy;

        float sy = ((float)y + 0.5f) * INVSCALEF - 0.5f;
        int jy = (int)floorf(sy);
        if (jy < 0) jy = 0; if (jy > HM - 2) jy = HM - 2;
        float fy = fminf(fmaxf(sy - (float)jy, 0.0f), 1.0f);
        const float wy1 = fy, wy0 = 1.0f - fy;

        const v4f a = *((const v4f*)(sig + (jy - r_lo) * HM + col4 * 4));
        const v4f bb = *((const v4f*)(sig + (jy - r_lo + 1) * HM + col4 * 4));
        v4f t;
        t.x = wy0 * a.x + wy1 * bb.x;
        t.y = wy0 * a.y + wy1 * bb.y;
        t.z = wy0 * a.z + wy1 * bb.z;
        t.w = wy0 * a.w + wy1 * bb.w;
        *((v4f*)(tmp + yy * HM + col4 * 4)) = t;
    }

    __syncthreads();

    // phase C: horizontal lerp + threshold + coalesced store (3 LDS reads/quad)
    if (tid < 240) {
        float* outp = outm + (size_t)mask_id * (OUTS * OUTS)
                           + (size_t)(ys + yy0) * OUTS + x0;
        #pragma unroll
        for (int it = 0; it < VROWS / 2; ++it) {
            const float* tr = tmp + (yy0 + it * 2) * HM;
            const float t0 = tr[c0];
            const float t1 = tr[c1];
            const float t2 = tr[c2];

            v4f res;
            #pragma unroll
            for (int j = 0; j < 4; ++j) {
                const float ta = ar[j] ? t1 : t0;
                const float tb = ar[j] ? t2 : t1;
                const float val = ta + fxr[j] * (tb - ta);
                res[j] = (val > 0.5f) ? 1.0f : 0.0f;
            }
            *((v4f*)(outp + (size_t)(it * 2) * OUTS)) = res;
        }
    }
}

// ---------------------------------------------------------------------------
extern "C" void kernel_launch(void* const* d_in, const int* in_sizes, int n_in,
                              void* d_out, int out_size, void* d_ws, size_t ws_size,
                              hipStream_t stream) {
    const float* logits = (const float*)d_in[0];   // [2,300,80]
    const float* boxes  = (const float*)d_in[1];   // [2,300,4]
    const float* masks  = (const float*)d_in[2];   // [2,300,128,128]
    const float* osize  = (const float*)d_in[3];   // [2,2]
    float* out = (float*)d_out;
    int* qidx = (int*)d_ws;                        // 600 ints

    topk_kernel<<<BATCH, 1024, 0, stream>>>(logits, boxes, osize, out, qidx);

    // masks start after scores(600) + labels(600) + boxes(2400) = 3600 floats
    mask_kernel<<<BATCH * TOPK * NVS, 256, 0, stream>>>(masks, qidx, out + 3600);
}

// Round 17
// 138.743 us; speedup vs baseline: 1.1418x; 1.0225x over previous
//
#include <hip/hip_runtime.h>
#include <math.h>

// Problem constants (fixed by the reference)
#define BATCH 2
#define NQ    300
#define NC    80
#define NFLAT (NQ * NC)     // 24000 per batch
#define TOPK  300
#define HM    128           // mask H=W
#define OUTS  480           // output H=W
#define NBKT  4096          // histogram buckets (top 12 bits of mapped float)
#define CAP   4096          // candidate capacity

#define INVSCALEF 0.26666668f  // 128/480 in f32; resize coords are never within
                               // 1/30 of an integer, so f32 floor/frac are exact

typedef float v4f __attribute__((ext_vector_type(4)));
typedef unsigned long long ull;

// order-preserving map: float bits -> uint32 (monotone in float value)
__device__ __forceinline__ unsigned mapf(float x) {
    unsigned u = __float_as_uint(x);
    return (u & 0x80000000u) ? ~u : (u | 0x80000000u);
}

// ---------------------------------------------------------------------------
// Kernel 1: FUSED top-k. One block per batch sample. (measured-best, R12)
// ---------------------------------------------------------------------------
__global__ __launch_bounds__(1024) void topk_kernel(
    const float* __restrict__ logits,   // [B,Q,C]
    const float* __restrict__ boxes,    // [B,Q,4] cxcywh
    const float* __restrict__ osize,    // [B,2]
    float* __restrict__ out,            // header region of d_out
    int* __restrict__ qidx)             // [B*K] scratch (ws)
{
    __shared__ unsigned hist[NBKT];              // 16 KB
    __shared__ unsigned long long cand[CAP];     // 32 KB
    __shared__ unsigned wtot[16];
    __shared__ unsigned ysuf[17];
    __shared__ unsigned sh_T;
    __shared__ unsigned sh_cnt;

    const int b = blockIdx.x;
    const int tid = threadIdx.x;
    const int lane = tid & 63;
    const int w = tid >> 6;
    const float* lg = logits + (size_t)b * NFLAT;
    const v4f* lg4 = (const v4f*)lg;

    // zero the histogram (each thread owns 4 consecutive buckets)
    *(uint4*)&hist[4 * tid] = make_uint4(0u, 0u, 0u, 0u);
    if (tid == 0) sh_cnt = 0;
    __syncthreads();

    // histogram of top 12 bits of the mapped float (float4 loads, LDS atomics)
    for (int i4 = tid; i4 < NFLAT / 4; i4 += 1024) {
        const v4f v = lg4[i4];
        atomicAdd(&hist[mapf(v.x) >> 20], 1u);
        atomicAdd(&hist[mapf(v.y) >> 20], 1u);
        atomicAdd(&hist[mapf(v.z) >> 20], 1u);
        atomicAdd(&hist[mapf(v.w) >> 20], 1u);
    }
    __syncthreads();

    // this thread's 4 buckets
    const uint4 h4 = *(const uint4*)&hist[4 * tid];
    const unsigned gsum = h4.x + h4.y + h4.z + h4.w;

    // wave-level inclusive suffix scan of gsum
    unsigned s = gsum;
    #pragma unroll
    for (int off = 1; off < 64; off <<= 1) {
        unsigned v = __shfl_down(s, off, 64);
        if (lane + off < 64) s += v;
    }
    if (lane == 0) wtot[w] = s;    // wave total
    __syncthreads();
    if (tid == 0) {                // suffix over 16 wave totals
        unsigned acc = 0;
        ysuf[16] = 0;
        for (int i = 15; i >= 0; --i) { acc += wtot[i]; ysuf[i] = acc; }
    }
    __syncthreads();
    const unsigned S   = s + ysuf[w + 1];  // #{elements in buckets >= 4*tid}
    const unsigned nxt = S - gsum;         // #{elements in buckets >  4*tid+3}
    if (S >= (unsigned)TOPK && nxt < (unsigned)TOPK) {
        unsigned acc = nxt, T;
        if (acc + h4.w >= (unsigned)TOPK) T = 4u * tid + 3u;
        else { acc += h4.w;
            if (acc + h4.z >= (unsigned)TOPK) T = 4u * tid + 2u;
            else { acc += h4.z;
                if (acc + h4.y >= (unsigned)TOPK) T = 4u * tid + 1u;
                else T = 4u * tid;
            }
        }
        sh_T = T;
    }
    __syncthreads();
    const unsigned T = sh_T;

    // collect candidates (bucket >= T): float4 loads (L2-warm);
    // keys = score desc, idx asc
    for (int i4 = tid; i4 < NFLAT / 4; i4 += 1024) {
        const v4f v = lg4[i4];
        #pragma unroll
        for (int j = 0; j < 4; ++j) {
            const unsigned m = mapf(v[j]);
            if ((m >> 20) >= T) {
                unsigned pos = atomicAdd(&sh_cnt, 1u);
                if (pos < CAP) {
                    const unsigned idx = 4u * i4 + j;
                    cand[pos] = ((ull)m << 32) | (ull)(0xFFFFFFFFu - idx);
                }
            }
        }
    }
    __syncthreads();
    const unsigned cnt = (sh_cnt > CAP) ? CAP : sh_cnt;

    // rank-select: rank = #{keys greater than mine}; ranks are unique.
    for (unsigned t = tid; t < cnt; t += 1024) {
        const unsigned long long my = cand[t];
        unsigned rank = 0;
        for (unsigned j = 0; j < cnt; ++j) rank += (cand[j] > my) ? 1u : 0u;
        if (rank < (unsigned)TOPK) {
            const unsigned idx = 0xFFFFFFFFu - (unsigned)(my & 0xFFFFFFFFull);
            const int q = (int)(idx / NC);
            const int c = (int)(idx % NC);
            const double x = (double)lg[idx];
            const double score = 1.0 / (1.0 + exp(-x));

            out[b * TOPK + rank] = (float)score;                   // top_scores
            out[BATCH * TOPK + b * TOPK + rank] = (float)c;        // top_labels

            const float* bx = boxes + ((size_t)(b * NQ + q)) * 4;
            const double cx = (double)bx[0], cy = (double)bx[1];
            const double bw = (double)bx[2], bh = (double)bx[3];
            const double s0 = (double)osize[b * 2 + 0];
            const double s1 = (double)osize[b * 2 + 1];
            float* ob = out + 2 * BATCH * TOPK + ((size_t)(b * TOPK + rank)) * 4;
            ob[0] = (float)((cx - 0.5 * bw) * s0);
            ob[1] = (float)((cy - 0.5 * bh) * s1);
            ob[2] = (float)((cx + 0.5 * bw) * s0);
            ob[3] = (float)((cy + 0.5 * bh) * s1);

            qidx[b * TOPK + rank] = q;
        }
    }
}

// ---------------------------------------------------------------------------
// Kernel 2: gather masks, sigmoid, bilinear 128->480, threshold. All f32.
// One small block per (mask, 16-row slice): 600*30 = 18000 blocks x 256 thr.
// (exact R7/R8/R10/R12 measured-best version — byte-identical)
// ---------------------------------------------------------------------------
#define VROWS   16
#define NVS     (OUTS / VROWS)       // 30 slices per mask
#define MAXR    6                    // max source rows per slice

__global__ __launch_bounds__(256) void mask_kernel(
    const float* __restrict__ masks,   // [B,Q,128,128]
    const int* __restrict__ qidx,      // [B*K]
    float* __restrict__ outm)          // d_out + 3600, [B*K,480,480]
{
    __shared__ float sig[MAXR * HM];   // 3 KB

    const int tid = threadIdx.x;
    const int unit = blockIdx.x;
    const int mask_id = unit / NVS;
    const int vs = unit % NVS;
    const int ys = vs * VROWS;
    const int b = mask_id / TOPK;
    const int q = qidx[mask_id];

    // source row range for this slice (f32 floor is exact here)
    float s_first = ((float)ys + 0.5f) * INVSCALEF - 0.5f;
    float s_last  = ((float)(ys + VROWS - 1) + 0.5f) * INVSCALEF - 0.5f;
    int r_lo = (int)floorf(s_first);
    if (r_lo < 0) r_lo = 0; if (r_lo > HM - 2) r_lo = HM - 2;
    int r_hi = (int)floorf(s_last);
    if (r_hi < 0) r_hi = 0; if (r_hi > HM - 2) r_hi = HM - 2;
    r_hi += 1;
    const int cnt = r_hi - r_lo + 1;   // <= 6

    // stage source rows [r_lo, r_hi] as f32 sigmoid (one 16B load/thread)
    const v4f* s4 = (const v4f*)(masks
                      + ((size_t)(b * NQ + q)) * (HM * HM)
                      + (size_t)r_lo * HM);
    const int n4 = cnt * (HM / 4);     // <= 192
    if (tid < n4) {
        v4f v = s4[tid];
        float* dst = sig + tid * 4;
        dst[0] = 1.0f / (1.0f + __expf(-v.x));
        dst[1] = 1.0f / (1.0f + __expf(-v.y));
        dst[2] = 1.0f / (1.0f + __expf(-v.z));
        dst[3] = 1.0f / (1.0f + __expf(-v.w));
    }

    // per-thread column geometry (threads 0..239 active: 2 rows x 120 quads)
    const int qd = tid % 120;
    const int yy = tid / 120;          // 0 or 1
    const int x0 = qd * 4;
    int c0 = 0, ar[4];
    float fxr[4];
    #pragma unroll
    for (int j = 0; j < 4; ++j) {
        float sx = ((float)(x0 + j) + 0.5f) * INVSCALEF - 0.5f;
        int jx = (int)floorf(sx);
        if (jx < 0) jx = 0; if (jx > HM - 2) jx = HM - 2;
        float f = sx - (float)jx;
        f = fminf(fmaxf(f, 0.0f), 1.0f);
        if (j == 0) c0 = jx;
        ar[j]  = jx - c0;              // 0 or 1
        fxr[j] = f;
    }
    const int c1 = c0 + 1;
    const int c2 = (c0 + 2 > HM - 1) ? (HM - 1) : (c0 + 2);

    __syncthreads();

    if (tid < 240) {
        float* outp = outm + (size_t)mask_id * (OUTS * OUTS)
                           + (size_t)(ys + yy) * OUTS + x0;
        #pragma unroll
        for (int it = 0; it < VROWS / 2; ++it) {
            const int y = ys + yy + it * 2;
            float sy = ((float)y + 0.5f) * INVSCALEF - 0.5f;
            int jy = (int)floorf(sy);
            if (jy < 0) jy = 0; if (jy > HM - 2) jy = HM - 2;
            float fy = sy - (float)jy;
            fy = fminf(fmaxf(fy, 0.0f), 1.0f);

            const float* r0 = sig + (size_t)(jy - r_lo) * HM;
            const float* r1 = r0 + HM;
            const float wy1 = fy, wy0 = 1.0f - fy;

            const float t0 = wy0 * r0[c0] + wy1 * r1[c0];
            const float t1 = wy0 * r0[c1] + wy1 * r1[c1];
            const float t2 = wy0 * r0[c2] + wy1 * r1[c2];

            v4f res;
            #pragma unroll
            for (int j = 0; j < 4; ++j) {
                const float ta = ar[j] ? t1 : t0;
                const float tb = ar[j] ? t2 : t1;
                const float val = ta + fxr[j] * (tb - ta);
                res[j] = (val > 0.5f) ? 1.0f : 0.0f;
            }
            *((v4f*)(outp + (size_t)(it * 2) * OUTS)) = res;
        }
    }
}

// ---------------------------------------------------------------------------
extern "C" void kernel_launch(void* const* d_in, const int* in_sizes, int n_in,
                              void* d_out, int out_size, void* d_ws, size_t ws_size,
                              hipStream_t stream) {
    const float* logits = (const float*)d_in[0];   // [2,300,80]
    const float* boxes  = (const float*)d_in[1];   // [2,300,4]
    const float* masks  = (const float*)d_in[2];   // [2,300,128,128]
    const float* osize  = (const float*)d_in[3];   // [2,2]
    float* out = (float*)d_out;
    int* qidx = (int*)d_ws;                        // 600 ints

    topk_kernel<<<BATCH, 1024, 0, stream>>>(logits, boxes, osize, out, qidx);

    // masks start after scores(600) + labels(600) + boxes(2400) = 3600 floats
    mask_kernel<<<BATCH * TOPK * NVS, 256, 0, stream>>>(masks, qidx, out + 3600);
}